// Round 3
// baseline (55138.293 us; speedup 1.0000x reference)
//
#include <hip/hip_runtime.h>
#include <hip/hip_cooperative_groups.h>

namespace cg = cooperative_groups;

// Spiking LSTM (LIF gates), T=1024, N=32, I=H=1024, 4H=4096. Full f64 internals
// (round 1: absmax 0.0 — spike decisions exact; recurrent sum is exactly
// representable in f64, so summation order is irrelevant).
// Round-3 fixes vs round 2:
//   (a) hg ping-pong: read hg[t&1], write hg[(t+1)&1]  — kills inter-block race
//   (b) hipLaunchCooperativeKernel return checked; fallback = per-step regular
//       launches of the same kernel with gsync=0 (no grid.sync executed).

#define NBATCH 32
#define HID    1024
#define FH     4096
#define TK     1024
#define TT     1024
#define TNH    (TT * NBATCH * HID)   // 33554432

// ---------------- k_zero ----------------
__global__ __launch_bounds__(256) void k_zero(double* __restrict__ p, long n) {
    long i = blockIdx.x * 256L + threadIdx.x;
    long stride = (long)gridDim.x * 256L;
    for (; i < n; i += stride) p[i] = 0.0;
}

// ---------------- k_prep2: gather per-block Wh slices ----------------
// Whpp[b][k][col] = (double)Wh[g*1024 + b*4 + hl][k],  col = g*4 + hl
__global__ __launch_bounds__(256) void k_prep2(const float* __restrict__ Wh,
                                               double* __restrict__ Whpp) {
    __shared__ float t[16][1028];
    int b = blockIdx.x, tid = threadIdx.x;
    for (int r = 0; r < 16; ++r) {
        int g = r >> 2, hl = r & 3;
        const float* src = Wh + (size_t)(g * 1024 + b * 4 + hl) * TK;
        for (int k = tid; k < TK; k += 256) t[r][k] = src[k];
    }
    __syncthreads();
    double* dst = Whpp + (size_t)b * 16384;
    for (int i = 0; i < 64; ++i) {
        int lin = i * 256 + tid;             // 0..16383 = k*16 + col
        int k = lin >> 4, col = lin & 15;
        dst[lin] = (double)t[col][k];
    }
}

// ---------------- k_xgemm (unchanged; exact in round 1) ----------------
#define BK 16
__global__ __launch_bounds__(256) void k_xgemm(const float* __restrict__ X,
                                               const float* __restrict__ Wx,
                                               const float* __restrict__ bx,
                                               const float* __restrict__ bh,
                                               double* __restrict__ Gx) {
    __shared__ double Al[BK][130];
    __shared__ double Bl[BK][66];
    int tid = threadIdx.x;
    int j0 = blockIdx.x * 64;
    size_t m0 = (size_t)blockIdx.y * 128;

    double acc[8][4];
#pragma unroll
    for (int r = 0; r < 8; ++r)
#pragma unroll
        for (int c = 0; c < 4; ++c) acc[r][c] = 0.0;

    int mo4 = (tid & 15) * 4;
    int jo4 = (tid >> 4) * 4;
    int mm = tid >> 1, kh = (tid & 1) * 8;
    int jj = tid >> 2, kq = (tid & 3) * 4;

    for (int k0 = 0; k0 < TK; k0 += BK) {
        float4 fa0 = *(const float4*)(X + (m0 + mm) * TK + k0 + kh);
        float4 fa1 = *(const float4*)(X + (m0 + mm) * TK + k0 + kh + 4);
        float4 fb  = *(const float4*)(Wx + (size_t)(j0 + jj) * TK + k0 + kq);
        Al[kh + 0][mm] = fa0.x; Al[kh + 1][mm] = fa0.y;
        Al[kh + 2][mm] = fa0.z; Al[kh + 3][mm] = fa0.w;
        Al[kh + 4][mm] = fa1.x; Al[kh + 5][mm] = fa1.y;
        Al[kh + 6][mm] = fa1.z; Al[kh + 7][mm] = fa1.w;
        Bl[kq + 0][jj] = fb.x; Bl[kq + 1][jj] = fb.y;
        Bl[kq + 2][jj] = fb.z; Bl[kq + 3][jj] = fb.w;
        __syncthreads();
#pragma unroll
        for (int kk = 0; kk < BK; ++kk) {
            double a[8], bb[4];
#pragma unroll
            for (int i = 0; i < 4; ++i) {
                a[i]     = Al[kk][mo4 + i];
                a[4 + i] = Al[kk][64 + mo4 + i];
                bb[i]    = Bl[kk][jo4 + i];
            }
#pragma unroll
            for (int r = 0; r < 8; ++r)
#pragma unroll
                for (int c = 0; c < 4; ++c) acc[r][c] += a[r] * bb[c];
        }
        __syncthreads();
    }

    double bsum[4];
#pragma unroll
    for (int c = 0; c < 4; ++c) {
        int j = j0 + jo4 + c;
        bsum[c] = (double)bx[j] + (double)bh[j];
    }
#pragma unroll
    for (int r = 0; r < 8; ++r) {
        int mloc = (r < 4) ? (mo4 + r) : (64 + mo4 + (r - 4));
        double* dst = Gx + (m0 + mloc) * FH + j0 + jo4;
#pragma unroll
        for (int c = 0; c < 4; ++c) dst[c] = acc[r][c] + bsum[c];
    }
}

// ---------------- k_steps: persistent per-timestep kernel ----------------
// 256 blocks x 512 threads. Block b owns hidden units 4b..4b+3 (16 gate cols).
// hg is DOUBLE-BUFFERED: read hg + (t&1)*32768, write hg + ((t+1)&1)*32768.
// gsync=1: cooperative (grid.sync per step). gsync=0: single-step launches.
__global__ __launch_bounds__(512) void k_steps(const double* __restrict__ Whpp,
                                               double* __restrict__ hg,
                                               double* __restrict__ stateg,
                                               const double* __restrict__ Gx,
                                               float* __restrict__ out,
                                               int t0, int ct, int gsync) {
    __shared__ __align__(16) double wlds[2][128 * 16];
    __shared__ __align__(16) double hlds[2][128 * 32];
    __shared__ __align__(16) double redbuf[8][512];

    int tid = threadIdx.x;
    int b = blockIdx.x;
    int wave = tid >> 6, lane = tid & 63;
    int cp = lane & 7;          // col pair: cols 2cp, 2cp+1
    int ng = lane >> 3;         // n group: n = 4ng..4ng+3
    int hl = tid & 3, nl = tid >> 2;   // LIF element (tid < 128)

    double vi = 0, vf = 0, vo = 0, vcs = 0, vct = 0, cc = 0;
    int u = nl * HID + b * 4 + hl;
    if (tid < 128) {
        vi  = stateg[u];
        vf  = stateg[32768 + u];
        vo  = stateg[65536 + u];
        vcs = stateg[98304 + u];
        vct = stateg[131072 + u];
        cc  = stateg[163840 + u];
    }
    const double* wsrc = Whpp + (size_t)b * 16384;

    for (int t = t0; t < t0 + ct; ++t) {
        const double* hgr = hg + (size_t)(t & 1) * 32768;        // read buffer
        double*       hgw = hg + (size_t)((t + 1) & 1) * 32768;  // write buffer

        double acc[4][2];
#pragma unroll
        for (int a = 0; a < 4; ++a) { acc[a][0] = 0.0; acc[a][1] = 0.0; }

        if (t > 0) {
            double2 rw0, rw1, rh0, rh1, rh2, rh3;
            {   // stage chunk 0
                const double2* gw = (const double2*)wsrc;
                const double2* gh = (const double2*)hgr;
                rw0 = gw[tid]; rw1 = gw[512 + tid];
                rh0 = gh[tid]; rh1 = gh[512 + tid];
                rh2 = gh[1024 + tid]; rh3 = gh[1536 + tid];
                double2* dw = (double2*)wlds[0];
                double2* dh = (double2*)hlds[0];
                dw[tid] = rw0; dw[512 + tid] = rw1;
                dh[tid] = rh0; dh[512 + tid] = rh1;
                dh[1024 + tid] = rh2; dh[1536 + tid] = rh3;
            }
            for (int c = 0; c < 8; ++c) {
                __syncthreads();               // staged buf c visible to all
                int buf = c & 1;
                if (c < 7) {                   // issue next chunk's global loads
                    const double2* gw = (const double2*)(wsrc + (c + 1) * 2048);
                    const double2* gh = (const double2*)(hgr + (c + 1) * 4096);
                    rw0 = gw[tid]; rw1 = gw[512 + tid];
                    rh0 = gh[tid]; rh1 = gh[512 + tid];
                    rh2 = gh[1024 + tid]; rh3 = gh[1536 + tid];
                }
                const double* wb = wlds[buf];
                const double* hb = hlds[buf];
#pragma unroll
                for (int kk = 0; kk < 16; ++kk) {
                    int k = wave * 16 + kk;
                    double2 wv  = *(const double2*)&wb[k * 16 + cp * 2];
                    double2 h01 = *(const double2*)&hb[k * 32 + ng * 4];
                    double2 h23 = *(const double2*)&hb[k * 32 + ng * 4 + 2];
                    acc[0][0] += h01.x * wv.x; acc[0][1] += h01.x * wv.y;
                    acc[1][0] += h01.y * wv.x; acc[1][1] += h01.y * wv.y;
                    acc[2][0] += h23.x * wv.x; acc[2][1] += h23.x * wv.y;
                    acc[3][0] += h23.y * wv.x; acc[3][1] += h23.y * wv.y;
                }
                if (c < 7) {
                    int nbuf = buf ^ 1;
                    double2* dw = (double2*)wlds[nbuf];
                    double2* dh = (double2*)hlds[nbuf];
                    dw[tid] = rw0; dw[512 + tid] = rw1;
                    dh[tid] = rh0; dh[512 + tid] = rh1;
                    dh[1024 + tid] = rh2; dh[1536 + tid] = rh3;
                }
            }
        }

        // per-wave partials -> LDS
#pragma unroll
        for (int a = 0; a < 4; ++a) {
            int n = ng * 4 + a;
            redbuf[wave][(cp * 2 + 0) * 32 + n] = acc[a][0];
            redbuf[wave][(cp * 2 + 1) * 32 + n] = acc[a][1];
        }
        __syncthreads();

        if (tid < 128) {
            int tl = t - t0;
            double g[4];
#pragma unroll
            for (int gi = 0; gi < 4; ++gi) {
                int col = gi * 4 + hl;
                double s = Gx[((size_t)tl * NBATCH + nl) * FH + gi * 1024 + b * 4 + hl];
#pragma unroll
                for (int w = 0; w < 8; ++w) s += redbuf[w][col * 32 + nl];
                g[gi] = s;
            }
            // LIF (same f64 expression tree as round 1 — exact match)
            double v, si, sf, so, scs, sct;
            v = vi;  v = v + (g[0] - v) * 0.5;
            si  = ((v - 0.1) >= 0.0) ? 1.0 : 0.0;  vi  = (1.0 - si)  * v;
            v = vf;  v = v + (g[2] - v) * 0.5;
            sf  = ((v - 0.1) >= 0.0) ? 1.0 : 0.0;  vf  = (1.0 - sf)  * v;
            v = vo;  v = v + (g[1] - v) * 0.5;
            so  = ((v - 0.1) >= 0.0) ? 1.0 : 0.0;  vo  = (1.0 - so)  * v;
            v = vcs; v = v + (g[3] - v) * 0.5;
            scs = ((v - 0.1) >= 0.0) ? 1.0 : 0.0;  vcs = (1.0 - scs) * v;
            cc = sf * cc + si * scs;
            v = vct; v = v + (cc - v) * 0.5;
            sct = ((v - 0.1) >= 0.0) ? 1.0 : 0.0;  vct = (1.0 - sct) * v;
            double h = so * sct;

            hgw[(b * 4 + hl) * 32 + nl] = h;                   // hg[k][n]
            out[(size_t)t * (NBATCH * HID) + nl * HID + b * 4 + hl] = (float)h;
            if (t == TT - 1) {
                out[(size_t)TNH + nl * HID + b * 4 + hl] = (float)h;
                out[(size_t)TNH + NBATCH * HID + nl * HID + b * 4 + hl] = (float)cc;
            }
        }
        if (gsync) cg::this_grid().sync();
    }

    if (tid < 128) {
        stateg[u]          = vi;
        stateg[32768 + u]  = vf;
        stateg[65536 + u]  = vo;
        stateg[98304 + u]  = vcs;
        stateg[131072 + u] = vct;
        stateg[163840 + u] = cc;
    }
}

extern "C" void kernel_launch(void* const* d_in, const int* in_sizes, int n_in,
                              void* d_out, int out_size, void* d_ws, size_t ws_size,
                              hipStream_t stream) {
    (void)in_sizes; (void)n_in; (void)out_size;
    const float* X  = (const float*)d_in[0];
    const float* Wx = (const float*)d_in[1];
    const float* bx = (const float*)d_in[2];
    const float* Wh = (const float*)d_in[3];
    const float* bh = (const float*)d_in[4];
    float* out = (float*)d_out;

    double* ws     = (double*)d_ws;
    double* Whpp   = ws;                       // 256*16384 = 4,194,304 doubles
    double* stateg = Whpp + 4194304;           // 6*32768 = 196,608
    double* hg     = stateg + 196608;          // 2*32768 = 65,536 (ping-pong)
    double* Gx     = hg + 65536;               // ct*131072

    size_t fixedB = (4194304ULL + 196608ULL + 65536ULL) * 8;
    int ct = 8;
    for (int cand = 1024; cand >= 8; cand >>= 1) {
        if (fixedB + (size_t)cand * NBATCH * FH * 8 <= ws_size) { ct = cand; break; }
    }
    int nchunk = TT / ct;

    hipLaunchKernelGGL(k_zero, dim3(64), dim3(256), 0, stream, stateg, 196608L);
    hipLaunchKernelGGL(k_prep2, dim3(256), dim3(256), 0, stream, Wh, Whpp);

    for (int c = 0; c < nchunk; ++c) {
        const float* Xc = X + (size_t)c * ct * NBATCH * TK;
        hipLaunchKernelGGL(k_xgemm, dim3(64, (ct * NBATCH) / 128), dim3(256), 0, stream,
                           Xc, Wx, bx, bh, Gx);
        int t0 = c * ct;
        const double* whpp_a = Whpp;
        double* hg_a = hg;
        double* st_a = stateg;
        const double* gx_a = Gx;
        float* out_a = out;
        int one = 1;
        void* args[] = { (void*)&whpp_a, (void*)&hg_a, (void*)&st_a,
                         (void*)&gx_a, (void*)&out_a, (void*)&t0, (void*)&ct,
                         (void*)&one };
        hipError_t e = hipLaunchCooperativeKernel((const void*)k_steps, dim3(256),
                                                  dim3(512), args, 0, stream);
        if (e != hipSuccess) {
            // fallback: one regular launch per step (no grid.sync executed)
            for (int tl = 0; tl < ct; ++tl) {
                int t = t0 + tl;
                hipLaunchKernelGGL(k_steps, dim3(256), dim3(512), 0, stream,
                                   Whpp, hg, stateg, Gx + (size_t)tl * NBATCH * FH,
                                   out, t, 1, 0);
            }
        }
    }
}

// Round 4
// 50540.131 us; speedup vs baseline: 1.0910x; 1.0910x over previous
//
#include <hip/hip_runtime.h>
#include <hip/hip_cooperative_groups.h>

namespace cg = cooperative_groups;

// Spiking LSTM (LIF gates), T=1024, N=32, I=H=1024, 4H=4096. f64 internals
// (rounds 1/3: absmax 0.0 — spike decisions exact, order-insensitive at f64).
// Round-4 change: recurrent weights W are f32 and LDS-RESIDENT for the whole
// persistent kernel (round 3 re-fetched 33.5MB of f64 W per step -> 75% of
// time at 563 GB/s). h*w with h in {0,1} is an exact select; f64 accumulate
// of f32-valued addends keeps the result identical at f64 precision.
//   k_zero  : zero LIF states
//   k_prep2f: Whf[b][k*16+col] = Wh[g*1024 + b*4 + hl][k]  (f32, col=g*4+hl)
//   k_xgemm : Gx = X@Wx.T + bx + bh  (f64 acc, chunked by ws)
//   k_steps : persistent coop kernel; W resident (64KB f32 LDS); per step:
//             h staged in 16 x 16KB dbuf chunks; rec GEMM; fused LIF.

#define NBATCH 32
#define HID    1024
#define FH     4096
#define TK     1024
#define TT     1024
#define TNH    (TT * NBATCH * HID)   // 33554432

// ---------------- k_zero ----------------
__global__ __launch_bounds__(256) void k_zero(double* __restrict__ p, long n) {
    long i = blockIdx.x * 256L + threadIdx.x;
    long stride = (long)gridDim.x * 256L;
    for (; i < n; i += stride) p[i] = 0.0;
}

// ---------------- k_prep2f: gather per-block Wh slices (f32) ----------------
__global__ __launch_bounds__(256) void k_prep2f(const float* __restrict__ Wh,
                                                float* __restrict__ Whf) {
    __shared__ float t[16][1028];
    int b = blockIdx.x, tid = threadIdx.x;
    for (int r = 0; r < 16; ++r) {           // r = col = g*4 + hl
        int g = r >> 2, hl = r & 3;
        const float* src = Wh + (size_t)(g * 1024 + b * 4 + hl) * TK;
        for (int k = tid; k < TK; k += 256) t[r][k] = src[k];
    }
    __syncthreads();
    float* dst = Whf + (size_t)b * 16384;
    for (int i = 0; i < 64; ++i) {
        int lin = i * 256 + tid;             // 0..16383 = k*16 + col
        int k = lin >> 4, col = lin & 15;
        dst[lin] = t[col][k];
    }
}

// ---------------- k_xgemm (unchanged; exact since round 1) ----------------
#define BK 16
__global__ __launch_bounds__(256) void k_xgemm(const float* __restrict__ X,
                                               const float* __restrict__ Wx,
                                               const float* __restrict__ bx,
                                               const float* __restrict__ bh,
                                               double* __restrict__ Gx) {
    __shared__ double Al[BK][130];
    __shared__ double Bl[BK][66];
    int tid = threadIdx.x;
    int j0 = blockIdx.x * 64;
    size_t m0 = (size_t)blockIdx.y * 128;

    double acc[8][4];
#pragma unroll
    for (int r = 0; r < 8; ++r)
#pragma unroll
        for (int c = 0; c < 4; ++c) acc[r][c] = 0.0;

    int mo4 = (tid & 15) * 4;
    int jo4 = (tid >> 4) * 4;
    int mm = tid >> 1, kh = (tid & 1) * 8;
    int jj = tid >> 2, kq = (tid & 3) * 4;

    for (int k0 = 0; k0 < TK; k0 += BK) {
        float4 fa0 = *(const float4*)(X + (m0 + mm) * TK + k0 + kh);
        float4 fa1 = *(const float4*)(X + (m0 + mm) * TK + k0 + kh + 4);
        float4 fb  = *(const float4*)(Wx + (size_t)(j0 + jj) * TK + k0 + kq);
        Al[kh + 0][mm] = fa0.x; Al[kh + 1][mm] = fa0.y;
        Al[kh + 2][mm] = fa0.z; Al[kh + 3][mm] = fa0.w;
        Al[kh + 4][mm] = fa1.x; Al[kh + 5][mm] = fa1.y;
        Al[kh + 6][mm] = fa1.z; Al[kh + 7][mm] = fa1.w;
        Bl[kq + 0][jj] = fb.x; Bl[kq + 1][jj] = fb.y;
        Bl[kq + 2][jj] = fb.z; Bl[kq + 3][jj] = fb.w;
        __syncthreads();
#pragma unroll
        for (int kk = 0; kk < BK; ++kk) {
            double a[8], bb[4];
#pragma unroll
            for (int i = 0; i < 4; ++i) {
                a[i]     = Al[kk][mo4 + i];
                a[4 + i] = Al[kk][64 + mo4 + i];
                bb[i]    = Bl[kk][jo4 + i];
            }
#pragma unroll
            for (int r = 0; r < 8; ++r)
#pragma unroll
                for (int c = 0; c < 4; ++c) acc[r][c] += a[r] * bb[c];
        }
        __syncthreads();
    }

    double bsum[4];
#pragma unroll
    for (int c = 0; c < 4; ++c) {
        int j = j0 + jo4 + c;
        bsum[c] = (double)bx[j] + (double)bh[j];
    }
#pragma unroll
    for (int r = 0; r < 8; ++r) {
        int mloc = (r < 4) ? (mo4 + r) : (64 + mo4 + (r - 4));
        double* dst = Gx + (m0 + mloc) * FH + j0 + jo4;
#pragma unroll
        for (int c = 0; c < 4; ++c) dst[c] = acc[r][c] + bsum[c];
    }
}

// ---------------- k_steps: persistent per-timestep kernel ----------------
// 256 blocks x 512 threads. Block b owns hidden units 4b..4b+3 (16 gate cols).
// W resident in LDS (f32, [k][16c]). h ping-pong in global, staged per step
// in 16 chunks of 64 k (16KB), double-buffered. hg layout: [k=h-index][n].
__global__ __launch_bounds__(512) void k_steps(const float* __restrict__ Whf,
                                               double* __restrict__ hg,
                                               double* __restrict__ stateg,
                                               const double* __restrict__ Gx,
                                               float* __restrict__ out,
                                               int t0, int ct, int gsync) {
    __shared__ __align__(16) float  wres[16384];     // 64KB, [k][16c]
    __shared__ __align__(16) double hlds[2][2048];   // 2 x 16KB, [64k][32n]
    __shared__ __align__(16) double redbuf[8][512];  // 32KB

    int tid = threadIdx.x;
    int b = blockIdx.x;
    int wave = tid >> 6, lane = tid & 63;
    int cp = lane & 7;          // col pair: cols 2cp, 2cp+1
    int ng = lane >> 3;         // n group: n = 4ng..4ng+3
    int hl = tid & 3, nl = tid >> 2;   // LIF element (tid < 128)

    // W resident load (once)
    {
        const float4* src = (const float4*)(Whf + (size_t)b * 16384);
        float4* dst = (float4*)wres;
#pragma unroll
        for (int i = 0; i < 8; ++i) dst[i * 512 + tid] = src[i * 512 + tid];
    }

    double vi = 0, vf = 0, vo = 0, vcs = 0, vct = 0, cc = 0;
    int u = nl * HID + b * 4 + hl;
    if (tid < 128) {
        vi  = stateg[u];
        vf  = stateg[32768 + u];
        vo  = stateg[65536 + u];
        vcs = stateg[98304 + u];
        vct = stateg[131072 + u];
        cc  = stateg[163840 + u];
    }
    __syncthreads();    // wres visible

    for (int t = t0; t < t0 + ct; ++t) {
        const double* hgr = hg + (size_t)(t & 1) * 32768;        // read buffer
        double*       hgw = hg + (size_t)((t + 1) & 1) * 32768;  // write buffer

        double acc[4][2];
#pragma unroll
        for (int a = 0; a < 4; ++a) { acc[a][0] = 0.0; acc[a][1] = 0.0; }

        if (t > 0) {
            const double2* gh = (const double2*)hgr;
            double2 rh0 = gh[tid], rh1 = gh[512 + tid];
            { double2* dh = (double2*)hlds[0]; dh[tid] = rh0; dh[512 + tid] = rh1; }
            for (int c = 0; c < 16; ++c) {
                __syncthreads();               // staged buf c visible
                int buf = c & 1;
                if (c < 15) {                  // issue next chunk's loads
                    rh0 = gh[(c + 1) * 1024 + tid];
                    rh1 = gh[(c + 1) * 1024 + 512 + tid];
                }
                const double* hb = hlds[buf];
                const float* wrow = wres + (c * 64 + wave * 8) * 16 + cp * 2;
#pragma unroll
                for (int kk = 0; kk < 8; ++kk) {
                    float2 wf = *(const float2*)(wrow + kk * 16);
                    double w0 = (double)wf.x, w1 = (double)wf.y;
                    int kl = wave * 8 + kk;
                    double2 h01 = *(const double2*)&hb[kl * 32 + ng * 4];
                    double2 h23 = *(const double2*)&hb[kl * 32 + ng * 4 + 2];
                    acc[0][0] += h01.x * w0; acc[0][1] += h01.x * w1;
                    acc[1][0] += h01.y * w0; acc[1][1] += h01.y * w1;
                    acc[2][0] += h23.x * w0; acc[2][1] += h23.x * w1;
                    acc[3][0] += h23.y * w0; acc[3][1] += h23.y * w1;
                }
                if (c < 15) {                  // write staged regs to other buf
                    double2* dh = (double2*)hlds[buf ^ 1];
                    dh[tid] = rh0; dh[512 + tid] = rh1;
                }
            }
        }

        // per-wave partials -> LDS
#pragma unroll
        for (int a = 0; a < 4; ++a) {
            int n = ng * 4 + a;
            redbuf[wave][(cp * 2 + 0) * 32 + n] = acc[a][0];
            redbuf[wave][(cp * 2 + 1) * 32 + n] = acc[a][1];
        }
        __syncthreads();

        if (tid < 128) {
            int tl = t - t0;
            double g[4];
#pragma unroll
            for (int gi = 0; gi < 4; ++gi) {
                int col = gi * 4 + hl;
                double s = Gx[((size_t)tl * NBATCH + nl) * FH + gi * 1024 + b * 4 + hl];
#pragma unroll
                for (int w = 0; w < 8; ++w) s += redbuf[w][col * 32 + nl];
                g[gi] = s;
            }
            // LIF (same f64 expression tree as rounds 1/3 — exact match)
            double v, si, sf, so, scs, sct;
            v = vi;  v = v + (g[0] - v) * 0.5;
            si  = ((v - 0.1) >= 0.0) ? 1.0 : 0.0;  vi  = (1.0 - si)  * v;
            v = vf;  v = v + (g[2] - v) * 0.5;
            sf  = ((v - 0.1) >= 0.0) ? 1.0 : 0.0;  vf  = (1.0 - sf)  * v;
            v = vo;  v = v + (g[1] - v) * 0.5;
            so  = ((v - 0.1) >= 0.0) ? 1.0 : 0.0;  vo  = (1.0 - so)  * v;
            v = vcs; v = v + (g[3] - v) * 0.5;
            scs = ((v - 0.1) >= 0.0) ? 1.0 : 0.0;  vcs = (1.0 - scs) * v;
            cc = sf * cc + si * scs;
            v = vct; v = v + (cc - v) * 0.5;
            sct = ((v - 0.1) >= 0.0) ? 1.0 : 0.0;  vct = (1.0 - sct) * v;
            double h = so * sct;

            hgw[(b * 4 + hl) * 32 + nl] = h;                   // hg[k][n]
            out[(size_t)t * (NBATCH * HID) + nl * HID + b * 4 + hl] = (float)h;
            if (t == TT - 1) {
                out[(size_t)TNH + nl * HID + b * 4 + hl] = (float)h;
                out[(size_t)TNH + NBATCH * HID + nl * HID + b * 4 + hl] = (float)cc;
            }
        }
        if (gsync) cg::this_grid().sync();
    }

    if (tid < 128) {
        stateg[u]          = vi;
        stateg[32768 + u]  = vf;
        stateg[65536 + u]  = vo;
        stateg[98304 + u]  = vcs;
        stateg[131072 + u] = vct;
        stateg[163840 + u] = cc;
    }
}

extern "C" void kernel_launch(void* const* d_in, const int* in_sizes, int n_in,
                              void* d_out, int out_size, void* d_ws, size_t ws_size,
                              hipStream_t stream) {
    (void)in_sizes; (void)n_in; (void)out_size;
    const float* X  = (const float*)d_in[0];
    const float* Wx = (const float*)d_in[1];
    const float* bx = (const float*)d_in[2];
    const float* Wh = (const float*)d_in[3];
    const float* bh = (const float*)d_in[4];
    float* out = (float*)d_out;

    // workspace layout (double units; Whf is f32 = 2,097,152 double-slots)
    double* ws     = (double*)d_ws;
    float*  Whf    = (float*)ws;               // 256*16384 f32 = 16MB
    double* stateg = ws + 2097152;             // 6*32768 = 196,608
    double* hg     = stateg + 196608;          // 2*32768 = 65,536 (ping-pong)
    double* Gx     = hg + 65536;               // ct*131072

    size_t fixedB = (2097152ULL + 196608ULL + 65536ULL) * 8;
    int ct = 8;
    for (int cand = 1024; cand >= 8; cand >>= 1) {
        if (fixedB + (size_t)cand * NBATCH * FH * 8 <= ws_size) { ct = cand; break; }
    }
    int nchunk = TT / ct;

    hipLaunchKernelGGL(k_zero, dim3(64), dim3(256), 0, stream, stateg, 196608L);
    hipLaunchKernelGGL(k_prep2f, dim3(256), dim3(256), 0, stream, Wh, Whf);

    for (int c = 0; c < nchunk; ++c) {
        const float* Xc = X + (size_t)c * ct * NBATCH * TK;
        hipLaunchKernelGGL(k_xgemm, dim3(64, (ct * NBATCH) / 128), dim3(256), 0, stream,
                           Xc, Wx, bx, bh, Gx);
        int t0 = c * ct;
        const float* whf_a = Whf;
        double* hg_a = hg;
        double* st_a = stateg;
        const double* gx_a = Gx;
        float* out_a = out;
        int one = 1;
        void* args[] = { (void*)&whf_a, (void*)&hg_a, (void*)&st_a,
                         (void*)&gx_a, (void*)&out_a, (void*)&t0, (void*)&ct,
                         (void*)&one };
        hipError_t e = hipLaunchCooperativeKernel((const void*)k_steps, dim3(256),
                                                  dim3(512), args, 0, stream);
        if (e != hipSuccess) {
            // fallback: one regular launch per step (no grid.sync executed)
            for (int tl = 0; tl < ct; ++tl) {
                int t = t0 + tl;
                hipLaunchKernelGGL(k_steps, dim3(256), dim3(512), 0, stream,
                                   Whf, hg, stateg, Gx + (size_t)tl * NBATCH * FH,
                                   out, t, 1, 0);
            }
        }
    }
}